// Round 13
// baseline (441.649 us; speedup 1.0000x reference)
//
#include <hip/hip_runtime.h>

typedef __bf16 bf16_t;
typedef bf16_t bf16x4 __attribute__((ext_vector_type(4)));
typedef bf16_t bf16x8 __attribute__((ext_vector_type(8)));
typedef float f32x4 __attribute__((ext_vector_type(4)));

#define DD 1024
#define TT 4096

__device__ __forceinline__ void gload16(const void* g, void* l) {
    __builtin_amdgcn_global_load_lds(
        (const __attribute__((address_space(1))) void*)g,
        (__attribute__((address_space(3))) void*)l, 16, 0, 0);
}

// ---------------- merged fp32 -> bf16 convert: wa | wop | wdn ----------------
__global__ __launch_bounds__(256) void cvt3_k(const float* __restrict__ s0,
                                              const float* __restrict__ s1,
                                              const float* __restrict__ s2,
                                              bf16_t* __restrict__ d0,
                                              bf16_t* __restrict__ d1,
                                              bf16_t* __restrict__ d2) {
    const int i = (blockIdx.x * 256 + threadIdx.x) * 4;
    const float* s; bf16_t* d; int off;
    if (i < 1048576)            { s = s0; d = d0; off = i; }
    else if (i < 2097152)       { s = s1; d = d1; off = i - 1048576; }
    else                        { s = s2; d = d2; off = i - 2097152; }
    const float4 v = *(const float4*)(s + off);
    bf16x4 o;
    o[0] = (bf16_t)v.x; o[1] = (bf16_t)v.y; o[2] = (bf16_t)v.z; o[3] = (bf16_t)v.w;
    *(bf16x4*)(d + off) = o;
}

// ---------------- merged interleave convert: wiv | wgu ----------------
__global__ __launch_bounds__(256) void cvt_ilv2_k(const float* __restrict__ wi,
                                                  const float* __restrict__ wv,
                                                  bf16_t* __restrict__ wivb,
                                                  const float* __restrict__ wgu,
                                                  bf16_t* __restrict__ wgub) {
    const int i = (blockIdx.x * 256 + threadIdx.x) * 4;
    const float* src; bf16_t* dst; int idx;
    if (i < 2097152) {
        idx = i;
        const int rp = idx >> 10, k = idx & 1023, c = rp >> 1;
        src = ((rp & 1) ? wv : wi) + (long)c * 1024 + k;
        dst = wivb + idx;
    } else {
        idx = i - 2097152;
        const int rp = idx >> 10, k = idx & 1023, c = rp >> 1;
        src = ((rp & 1) ? (wgu + 4194304) : wgu) + (long)c * 1024 + k;
        dst = wgub + idx;
    }
    const float4 v = *(const float4*)src;
    bf16x4 o;
    o[0] = (bf16_t)v.x; o[1] = (bf16_t)v.y; o[2] = (bf16_t)v.z; o[3] = (bf16_t)v.w;
    *(bf16x4*)dst = o;
}

// ---------------- rmsnorm (1 block per row, 256 thr x 4 elems), bf16 out ----------------
__global__ __launch_bounds__(256) void rmsnorm_k(const float* __restrict__ x,
                                                 const float* __restrict__ w,
                                                 bf16_t* __restrict__ ob) {
    const long row = blockIdx.x;
    const float* xr = x + row * DD;
    const int t4 = threadIdx.x * 4;
    float4 v = *(const float4*)(xr + t4);
    float s = v.x*v.x + v.y*v.y + v.z*v.z + v.w*v.w;
    #pragma unroll
    for (int off = 1; off < 64; off <<= 1) s += __shfl_xor(s, off);
    __shared__ float red[4];
    if ((threadIdx.x & 63) == 0) red[threadIdx.x >> 6] = s;
    __syncthreads();
    float tot = red[0] + red[1] + red[2] + red[3];
    float sc = rsqrtf(tot * (1.0f / DD) + 1e-6f);
    float4 wv = *(const float4*)(w + t4);
    bf16x4 o;
    o[0] = (bf16_t)(v.x*sc*wv.x); o[1] = (bf16_t)(v.y*sc*wv.y);
    o[2] = (bf16_t)(v.z*sc*wv.z); o[3] = (bf16_t)(v.w*sc*wv.w);
    *(bf16x4*)(ob + row * DD + t4) = o;
}

// ---------------- causal depthwise conv K=4 (bf16 in, bf16 out) ----------------
__global__ __launch_bounds__(256) void conv_k(const bf16_t* __restrict__ h,
                                              const float* __restrict__ cw,
                                              const float* __restrict__ cb,
                                              bf16_t* __restrict__ hc) {
    const long idx = (long)blockIdx.x * 256 + threadIdx.x;  // over B*T*D
    const int d = (int)(idx & (DD - 1));
    const long bt = idx >> 10;
    const int t = (int)(bt & (TT - 1));
    const float w0 = cw[d*4+0], w1 = cw[d*4+1], w2 = cw[d*4+2], w3 = cw[d*4+3];
    const bf16_t* hp = h + bt * DD + d;
    float acc = cb[d] + (float)hp[0] * w3;
    if (t >= 1) acc += (float)hp[-DD]     * w2;
    if (t >= 2) acc += (float)hp[-2*DD]   * w1;
    if (t >= 3) acc += (float)hp[-3*DD]   * w0;
    hc[idx] = (bf16_t)acc;
}

// ---------------- scan pass1: per-chunk summaries (running-product cd) ----------------
__global__ __launch_bounds__(256) void scan1_k(const bf16_t* __restrict__ ap,
                                               const bf16_t* __restrict__ sp,
                                               float* __restrict__ cd63,
                                               float* __restrict__ i63) {
    const int d = blockIdx.x * 256 + threadIdx.x;  // 0..1023
    const int c = blockIdx.y;                      // chunk 0..63
    const int b = blockIdx.z;                      // batch
    const long rowbase = (long)b * TT + (long)c * 64;
    float cd = 1.0f, rs = 0.0f;
    for (int t = 0; t < 64; t++) {
        const long off = (rowbase + t) * DD + d;
        const float a = (float)ap[off];
        const float s = (float)sp[off];
        const float sig = __builtin_amdgcn_sqrtf(fmaxf(1.0f - a * a, 1e-8f)) * s;
        cd *= fmaxf(a, 1e-10f);
        rs = fmaf(sig, __builtin_amdgcn_rcpf(fmaxf(cd, 1e-10f)), rs);
    }
    const long o = ((long)b * 64 + c) * DD + d;
    cd63[o] = cd;
    i63[o]  = cd * rs;
}

// ---------------- pass2: cross-chunk carry (state ENTERING each chunk) ----------------
__global__ __launch_bounds__(256) void scan2_k(const float* __restrict__ cd63,
                                               const float* __restrict__ i63,
                                               float* __restrict__ carry_in) {
    const int g = blockIdx.x * 256 + threadIdx.x;  // 0..2047
    const int b = g >> 10, d = g & (DD - 1);
    float st = 0.0f;
    for (int c = 0; c < 64; c++) {
        const long o = ((long)b * 64 + c) * DD + d;
        carry_in[o] = st;
        st = i63[o] + cd63[o] * st;
    }
}

// ---------------- pass3: recompute chunk recurrence, fold carry, write bf16 ----------------
__global__ __launch_bounds__(256) void scan3_k(const bf16_t* __restrict__ ap,
                                               const bf16_t* __restrict__ sp,
                                               const float* __restrict__ carry_in,
                                               bf16_t* __restrict__ rec) {
    const int d = blockIdx.x * 256 + threadIdx.x;
    const int c = blockIdx.y;
    const int b = blockIdx.z;
    const long rowbase = (long)b * TT + (long)c * 64;
    const float carry = carry_in[((long)b * 64 + c) * DD + d];
    float cd = 1.0f, rs = 0.0f;
    for (int t = 0; t < 64; t++) {
        const long off = (rowbase + t) * DD + d;
        const float a = (float)ap[off];
        const float s = (float)sp[off];
        const float sig = __builtin_amdgcn_sqrtf(fmaxf(1.0f - a * a, 1e-8f)) * s;
        cd *= fmaxf(a, 1e-10f);
        rs = fmaf(sig, __builtin_amdgcn_rcpf(fmaxf(cd, 1e-10f)), rs);
        rec[off] = (bf16_t)(cd * (rs + carry));
    }
}

enum { EPI_SIGB = 0, EPI_ADDRES = 1, EPI_IV = 2, EPI_GU = 3 };

// ---------------- GEMM v1: 256xBN tile, 8 waves, 2-phase pre-read (R6) ----------------
// Used for iv (NREP=4) and gu (NREP=4): best rate for wide-N (763 TF measured).
template<int EPI, int NREP>
__global__ __launch_bounds__(512, 2) void gemm2p_k(const bf16_t* __restrict__ Ag,
                                                   const bf16_t* __restrict__ Bg,
                                                   int M, int N, int K,
                                                   float* outF, bf16_t* outB,
                                                   const float* aux, int ldc) {
    constexpr int BN  = NREP * 64;
    constexpr int ASZ = 16384;        // 256 x 64 bf16
    constexpr int BSZ = BN * 64;
    constexpr int BUF = ASZ + BSZ;
    extern __shared__ bf16_t smem[];  // [2][A | B]
    const int tid = threadIdx.x;
    const int l = tid & 63;
    const int w = tid >> 6;
    const int wm = w >> 2, wn = w & 3;

    const int gx = gridDim.x;
    const int gy = gridDim.y;
    const int lin = blockIdx.y * gx + blockIdx.x;
    long row0, col0;
    if ((gy & 7) == 0) {
        const int rpc = gy >> 3;
        const int q = lin >> 3;
        row0 = (long)((lin & 7) * rpc + q % rpc) * 256;
        col0 = (long)(q / rpc) * (long)BN;
    } else {
        row0 = (long)blockIdx.y * 256;
        col0 = (long)blockIdx.x * BN;
    }

    const int srow = l >> 3;
    const int scol = ((l & 7) ^ srow) * 8;   // pre-swizzled source column
    const long aBase = row0 + srow;
    const long bBase = col0 + srow;
    const int R0a = w * 32;
    const int R0b = w * (BN / 8);

    const int NT = K >> 6;
    f32x4 acc[8][NREP] = {};

    const int lq2 = (l >> 4) * 16;
    const int rA = wm * 128 + (l & 15);
    const int rB = wn * (NREP * 16) + (l & 15);
    const int eA0 = rA * 64 + ((lq2 ^ ((rA & 7) << 4)) >> 1);
    const int eB0 = ASZ + rB * 64 + ((lq2 ^ ((rB & 7) << 4)) >> 1);

    #define STAGE_A(tt, off)                                                          \
        { const long kgk = (long)(tt) * 64 + scol;                                    \
          _Pragma("unroll")                                                           \
          for (int i = 0; i < 4; i++)                                                 \
              gload16(Ag + (aBase + R0a + i * 8) * (long)K + kgk,                     \
                      &smem[(off) + (R0a + i * 8) * 64]); }
    #define STAGE_B(tt, off)                                                          \
        { const long kgk = (long)(tt) * 64 + scol;                                    \
          _Pragma("unroll")                                                           \
          for (int i = 0; i < NREP; i++)                                              \
              gload16(Bg + (bBase + R0b + i * 8) * (long)K + kgk,                     \
                      &smem[(off) + ASZ + (R0b + i * 8) * 64]); }

    STAGE_A(0, 0); STAGE_B(0, 0);
    STAGE_A(1, BUF); STAGE_B(1, BUF);
    if constexpr (NREP == 4) { asm volatile("s_waitcnt vmcnt(8)" ::: "memory"); }
    else                     { asm volatile("s_waitcnt vmcnt(6)" ::: "memory"); }
    asm volatile("s_barrier" ::: "memory");

    bf16x8 pA[2][4], pB[2][NREP];
    #pragma unroll
    for (int kk = 0; kk < 2; kk++) {
        const int xo = kk * 32;
        #pragma unroll
        for (int n = 0; n < NREP; n++)
            pB[kk][n] = *(const bf16x8*)&smem[(eB0 ^ xo) + n * 1024];
        #pragma unroll
        for (int m = 0; m < 4; m++)
            pA[kk][m] = *(const bf16x8*)&smem[(eA0 ^ xo) + m * 1024];
    }

    for (int t = 0; t < NT; t++) {
        const int co = (t & 1) ? BUF : 0;
        const int oo = BUF - co;
        bf16x8 a1[2][4];

        __builtin_amdgcn_s_setprio(1);
        #pragma unroll
        for (int kk = 0; kk < 2; kk++)
            #pragma unroll
            for (int m = 0; m < 4; m++)
                #pragma unroll
                for (int n = 0; n < NREP; n++)
                    acc[m][n] = __builtin_amdgcn_mfma_f32_16x16x32_bf16(pA[kk][m], pB[kk][n], acc[m][n], 0, 0, 0);
        __builtin_amdgcn_s_setprio(0);
        #pragma unroll
        for (int kk = 0; kk < 2; kk++) {
            const int xo = kk * 32;
            #pragma unroll
            for (int m = 0; m < 4; m++)
                a1[kk][m] = *(const bf16x8*)&smem[co + (eA0 ^ xo) + 4096 + m * 1024];
        }
        asm volatile("s_barrier" ::: "memory");

        if (t + 2 < NT) { STAGE_A(t + 2, co); STAGE_B(t + 2, co); }
        __builtin_amdgcn_s_setprio(1);
        #pragma unroll
        for (int kk = 0; kk < 2; kk++)
            #pragma unroll
            for (int m = 0; m < 4; m++)
                #pragma unroll
                for (int n = 0; n < NREP; n++)
                    acc[m + 4][n] = __builtin_amdgcn_mfma_f32_16x16x32_bf16(a1[kk][m], pB[kk][n], acc[m + 4][n], 0, 0, 0);
        __builtin_amdgcn_s_setprio(0);
        if (t + 2 < NT) {
            if constexpr (NREP == 4) { asm volatile("s_waitcnt vmcnt(8)" ::: "memory"); }
            else                     { asm volatile("s_waitcnt vmcnt(6)" ::: "memory"); }
        } else if (t + 1 < NT) {
            asm volatile("s_waitcnt vmcnt(0)" ::: "memory");
        }
        asm volatile("s_barrier" ::: "memory");
        if (t + 1 < NT) {
            #pragma unroll
            for (int kk = 0; kk < 2; kk++) {
                const int xo = kk * 32;
                #pragma unroll
                for (int n = 0; n < NREP; n++)
                    pB[kk][n] = *(const bf16x8*)&smem[oo + (eB0 ^ xo) + n * 1024];
                #pragma unroll
                for (int m = 0; m < 4; m++)
                    pA[kk][m] = *(const bf16x8*)&smem[oo + (eA0 ^ xo) + m * 1024];
            }
        }
    }
    #undef STAGE_A
    #undef STAGE_B

    #pragma unroll
    for (int m = 0; m < 8; m++) {
        const long r0 = row0 + wm * 128 + m * 16 + (l >> 4) * 4;
        #pragma unroll
        for (int n = 0; n < NREP; n++) {
            const long cc = col0 + wn * (NREP * 16) + n * 16 + (l & 15);
            f32x4 v = acc[m][n];
            #pragma unroll
            for (int j = 0; j < 4; j++) {
                const long r = r0 + j;
                const float xv = v[j];
                if (EPI == EPI_SIGB) {
                    outB[r * ldc + cc] = (bf16_t)(1.0f / (1.0f + __expf(-(xv + aux[cc]))));
                } else if (EPI == EPI_ADDRES) {
                    outF[r * ldc + cc] = xv + aux[r * ldc + cc];
                } else if (EPI == EPI_IV) {
                    const float px = __shfl_xor(xv, 1);
                    if ((l & 1) == 0)
                        outB[r * ldc + (cc >> 1)] = (bf16_t)(px / (1.0f + __expf(-xv)));
                } else {  // EPI_GU
                    const float px = __shfl_xor(xv, 1);
                    if ((l & 1) == 0)
                        outB[r * ldc + (cc >> 1)] = (bf16_t)(xv / (1.0f + __expf(-xv)) * px);
                }
            }
        }
    }
}

// ---------------- GEMM v2: 128x128 tile, 4 waves, 2 blocks/CU (R8) ----------------
// Used for N=1024 GEMMs (a, op, down): grid (8,64)=512 blocks = one full round
// at 2 blocks/CU; barrier-decoupled block pairs overlap LDS/MFMA bursts.
template<int EPI>
__global__ __launch_bounds__(256, 2) void gemm2b_k(const bf16_t* __restrict__ Ag,
                                                   const bf16_t* __restrict__ Bg,
                                                   int M, int N, int K,
                                                   float* outF, bf16_t* outB,
                                                   const float* aux, int ldc) {
    constexpr int ASZ = 8192;         // 128 x 64 bf16
    constexpr int BUF = 16384;        // A + B (elements)
    extern __shared__ bf16_t smem[];  // [2][A | B] = 64 KiB
    const int tid = threadIdx.x;
    const int l = tid & 63;
    const int w = tid >> 6;           // wave 0..3
    const int wm = w >> 1, wn = w & 1;

    const int gx = gridDim.x;
    const int gy = gridDim.y;
    const int lin = blockIdx.y * gx + blockIdx.x;
    long row0, col0;
    if ((gy & 7) == 0) {
        const int rpc = gy >> 3;
        const int q = lin >> 3;
        row0 = (long)((lin & 7) * rpc + q % rpc) * 128;
        col0 = (long)(q / rpc) * 128;
    } else {
        row0 = (long)blockIdx.y * 128;
        col0 = (long)blockIdx.x * 128;
    }

    const int srow = l >> 3;
    const int scol = ((l & 7) ^ srow) * 8;
    const long aBase = row0 + srow;
    const long bBase = col0 + srow;
    const int R0 = w * 32;

    const int NT = K >> 6;
    f32x4 acc[4][4] = {};

    const int lq2 = (l >> 4) * 16;
    const int rA = wm * 64 + (l & 15);
    const int rB = wn * 64 + (l & 15);
    const int eA0 = rA * 64 + ((lq2 ^ ((rA & 7) << 4)) >> 1);
    const int eB0 = ASZ + rB * 64 + ((lq2 ^ ((rB & 7) << 4)) >> 1);

    #define ST_A(tt, off, i)                                                        \
        gload16(Ag + (aBase + R0 + (i) * 8) * (long)K + (long)(tt) * 64 + scol,     \
                &smem[(off) + (R0 + (i) * 8) * 64])
    #define ST_B(tt, off, i)                                                        \
        gload16(Bg + (bBase + R0 + (i) * 8) * (long)K + (long)(tt) * 64 + scol,     \
                &smem[(off) + ASZ + (R0 + (i) * 8) * 64])
    #define BAR asm volatile("s_barrier" ::: "memory")

    #pragma unroll
    for (int i = 0; i < 4; i++) ST_B(0, 0, i);
    #pragma unroll
    for (int i = 0; i < 4; i++) ST_A(0, 0, i);
    #pragma unroll
    for (int i = 0; i < 4; i++) ST_B(1, BUF, i);
    asm volatile("s_waitcnt vmcnt(4)" ::: "memory");
    BAR;

    for (int t = 0; t < NT; t++) {
        const int cur = (t & 1) * BUF;
        const int oth = BUF - cur;
        bf16x8 bk[4], af[4];

        #pragma unroll
        for (int n = 0; n < 4; n++)
            bk[n] = *(const bf16x8*)&smem[cur + eB0 + n * 1024];
        #pragma unroll
        for (int m = 0; m < 4; m++)
            af[m] = *(const bf16x8*)&smem[cur + eA0 + m * 1024];
        if (t + 1 < NT) {
            #pragma unroll
            for (int i = 0; i < 4; i++) ST_A(t + 1, oth, i);
        }
        BAR;
        __builtin_amdgcn_s_setprio(1);
        #pragma unroll
        for (int m = 0; m < 4; m++)
            #pragma unroll
            for (int n = 0; n < 4; n++)
                acc[m][n] = __builtin_amdgcn_mfma_f32_16x16x32_bf16(af[m], bk[n], acc[m][n], 0, 0, 0);
        __builtin_amdgcn_s_setprio(0);
        BAR;

        #pragma unroll
        for (int n = 0; n < 4; n++)
            bk[n] = *(const bf16x8*)&smem[cur + (eB0 ^ 32) + n * 1024];
        #pragma unroll
        for (int m = 0; m < 4; m++)
            af[m] = *(const bf16x8*)&smem[cur + (eA0 ^ 32) + m * 1024];
        BAR;
        __builtin_amdgcn_s_setprio(1);
        #pragma unroll
        for (int m = 0; m < 4; m++)
            #pragma unroll
            for (int n = 0; n < 4; n++)
                acc[m][n] = __builtin_amdgcn_mfma_f32_16x16x32_bf16(af[m], bk[n], acc[m][n], 0, 0, 0);
        __builtin_amdgcn_s_setprio(0);
        if (t + 2 < NT) {
            #pragma unroll
            for (int i = 0; i < 4; i++) ST_B(t + 2, cur, i);
            asm volatile("s_waitcnt vmcnt(4)" ::: "memory");
        } else {
            asm volatile("s_waitcnt vmcnt(0)" ::: "memory");
        }
        BAR;
    }
    #undef ST_A
    #undef ST_B
    #undef BAR

    #pragma unroll
    for (int m = 0; m < 4; m++) {
        const long r0 = row0 + wm * 64 + m * 16 + (l >> 4) * 4;
        #pragma unroll
        for (int n = 0; n < 4; n++) {
            const long cc = col0 + wn * 64 + n * 16 + (l & 15);
            f32x4 v = acc[m][n];
            #pragma unroll
            for (int j = 0; j < 4; j++) {
                const long r = r0 + j;
                const float xv = v[j];
                if (EPI == EPI_SIGB) {
                    outB[r * ldc + cc] = (bf16_t)(1.0f / (1.0f + __expf(-(xv + aux[cc]))));
                } else {  // EPI_ADDRES
                    outF[r * ldc + cc] = xv + aux[r * ldc + cc];
                }
            }
        }
    }
}

extern "C" void kernel_launch(void* const* d_in, const int* in_sizes, int n_in,
                              void* d_out, int out_size, void* d_ws, size_t ws_size,
                              hipStream_t stream) {
    const float* x   = (const float*)d_in[0];
    const float* pnw = (const float*)d_in[1];
    const float* cw  = (const float*)d_in[2];
    const float* cb  = (const float*)d_in[3];
    const float* wa  = (const float*)d_in[4];
    const float* wi  = (const float*)d_in[5];
    const float* wv  = (const float*)d_in[6];
    const float* wop = (const float*)d_in[7];
    const float* db  = (const float*)d_in[8];
    const float* fnw = (const float*)d_in[9];
    const float* wgu = (const float*)d_in[10];
    const float* wdn = (const float*)d_in[11];
    float* out = (float*)d_out;

    // ---- workspace layout (total ~129.5 MiB) ----
    char* ws = (char*)d_ws;
    bf16_t* wab   = (bf16_t*)(ws + 0);            // 1024x1024 bf16
    bf16_t* wivb  = (bf16_t*)(ws + 2097152);      // 2048x1024 bf16 (i|v interleaved)
    bf16_t* wopb  = (bf16_t*)(ws + 6291456);      // 1024x1024 bf16
    bf16_t* wgub  = (bf16_t*)(ws + 8388608);      // 8192x1024 bf16 (gate|up interleaved)
    bf16_t* wdnb  = (bf16_t*)(ws + 25165824);     // 4096x1024 bf16
    bf16_t* hb    = (bf16_t*)(ws + 33554432);     // 8192x1024 bf16 (reused: hn)
    bf16_t* hn    = hb;
    bf16_t* hc    = (bf16_t*)(ws + 50331648);     // 8192x1024 bf16 (reused: rec)
    bf16_t* rec   = hc;
    bf16_t* a_b   = (bf16_t*)(ws + 67108864);     // 8192x1024 bf16 (a-plane)
    bf16_t* s_b   = (bf16_t*)(ws + 100663296);    // 8192x1024 bf16 (s-plane)
    bf16_t* act   = (bf16_t*)(ws + 67108864);     // 8192x4096 bf16 (overlays after scan)
    float*  cd63  = (float*)(ws + 134217728);
    float*  i63   = (float*)(ws + 134742016);
    float*  carry = (float*)(ws + 135266304);

    const int LDS4 = 131072;   // gemm2p NREP=4
    const int LDSB = 65536;    // gemm2b
    hipFuncSetAttribute((const void*)gemm2p_k<EPI_IV, 4>,   hipFuncAttributeMaxDynamicSharedMemorySize, LDS4);
    hipFuncSetAttribute((const void*)gemm2p_k<EPI_GU, 4>,   hipFuncAttributeMaxDynamicSharedMemorySize, LDS4);
    hipFuncSetAttribute((const void*)gemm2b_k<EPI_SIGB>,    hipFuncAttributeMaxDynamicSharedMemorySize, LDSB);
    hipFuncSetAttribute((const void*)gemm2b_k<EPI_ADDRES>,  hipFuncAttributeMaxDynamicSharedMemorySize, LDSB);

    // weight converts (merged: 2 kernels)
    cvt3_k    <<<6144, 256, 0, stream>>>(wa, wop, wdn, wab, wopb, wdnb);
    cvt_ilv2_k<<<10240, 256, 0, stream>>>(wi, wv, wivb, wgu, wgub);

    // pre-norm + conv
    rmsnorm_k<<<8192, 256, 0, stream>>>(x, pnw, hb);
    conv_k<<<32768, 256, 0, stream>>>(hb, cw, cb, hc);

    // a-plane (bf16): sigmoid(h*w_a^T + db)   [128^2 tile, 2 blocks/CU]
    gemm2b_k<EPI_SIGB><<<dim3(8, 64), 256, LDSB, stream>>>(hc, wab, 8192, 1024, 1024,
                                                           nullptr, a_b, db, 1024);
    // s-plane (bf16): sigmoid(h*w_i^T) * (h*w_v^T)
    gemm2p_k<EPI_IV, 4><<<dim3(8, 32), 512, LDS4, stream>>>(hc, wivb, 8192, 2048, 1024,
                                                            nullptr, s_b, nullptr, 1024);
    // chunked scan (reference's clipped formula; running-product cd)
    scan1_k<<<dim3(4, 64, 2), 256, 0, stream>>>(a_b, s_b, cd63, i63);
    scan2_k<<<8, 256, 0, stream>>>(cd63, i63, carry);
    scan3_k<<<dim3(4, 64, 2), 256, 0, stream>>>(a_b, s_b, carry, rec);

    // out_proj + residual -> d_out holds x2
    gemm2b_k<EPI_ADDRES><<<dim3(8, 64), 256, LDSB, stream>>>(rec, wopb, 8192, 1024, 1024,
                                                             out, nullptr, x, 1024);
    // ffn
    rmsnorm_k<<<8192, 256, 0, stream>>>(out, fnw, hn);
    gemm2p_k<EPI_GU, 4><<<dim3(32, 32), 512, LDS4, stream>>>(hn, wgub, 8192, 8192, 1024,
                                                             nullptr, act, nullptr, 4096);
    // down-proj + residual, in place on d_out
    gemm2b_k<EPI_ADDRES><<<dim3(8, 64), 256, LDSB, stream>>>(act, wdnb, 8192, 1024, 4096,
                                                             out, nullptr, out, 1024);
}

// Round 14
// 435.559 us; speedup vs baseline: 1.0140x; 1.0140x over previous
//
#include <hip/hip_runtime.h>

typedef __bf16 bf16_t;
typedef bf16_t bf16x4 __attribute__((ext_vector_type(4)));
typedef bf16_t bf16x8 __attribute__((ext_vector_type(8)));
typedef float f32x4 __attribute__((ext_vector_type(4)));

#define DD 1024
#define TT 4096

__device__ __forceinline__ void gload16(const void* g, void* l) {
    __builtin_amdgcn_global_load_lds(
        (const __attribute__((address_space(1))) void*)g,
        (__attribute__((address_space(3))) void*)l, 16, 0, 0);
}

// ---------------- merged weight convert: wa|wop|wdn linear + wiv|wgu interleave ----------------
// ranges (in 4-elem units of the 16M-element space):
//   [0,6M):   linear  wa(1M) | wop(1M) | wdn(4M)
//   [6M,8M):  interleave wi/wv -> wivb (2M)
//   [8M,16M): interleave wgu lo/hi -> wgub (8M)
__global__ __launch_bounds__(256) void cvt_all_k(const float* __restrict__ wa,
                                                 const float* __restrict__ wop,
                                                 const float* __restrict__ wdn,
                                                 const float* __restrict__ wi,
                                                 const float* __restrict__ wv,
                                                 const float* __restrict__ wgu,
                                                 bf16_t* __restrict__ wab,
                                                 bf16_t* __restrict__ wopb,
                                                 bf16_t* __restrict__ wdnb,
                                                 bf16_t* __restrict__ wivb,
                                                 bf16_t* __restrict__ wgub) {
    const long i = ((long)blockIdx.x * 256 + threadIdx.x) * 4;
    const float* src; bf16_t* dst;
    if (i < 1048576)        { src = wa  + i;            dst = wab  + i; }
    else if (i < 2097152)   { src = wop + (i - 1048576); dst = wopb + (i - 1048576); }
    else if (i < 6291456)   { src = wdn + (i - 2097152); dst = wdnb + (i - 2097152); }
    else if (i < 8388608) {
        const long idx = i - 6291456;
        const int rp = (int)(idx >> 10), k = (int)(idx & 1023), c = rp >> 1;
        src = ((rp & 1) ? wv : wi) + (long)c * 1024 + k;
        dst = wivb + idx;
    } else {
        const long idx = i - 8388608;
        const int rp = (int)(idx >> 10), k = (int)(idx & 1023), c = rp >> 1;
        src = ((rp & 1) ? (wgu + 4194304) : wgu) + (long)c * 1024 + k;
        dst = wgub + idx;
    }
    const float4 v = *(const float4*)src;
    bf16x4 o;
    o[0] = (bf16_t)v.x; o[1] = (bf16_t)v.y; o[2] = (bf16_t)v.z; o[3] = (bf16_t)v.w;
    *(bf16x4*)dst = o;
}

// ---------------- rmsnorm (1 block per row, 256 thr x 4 elems), bf16 out ----------------
__global__ __launch_bounds__(256) void rmsnorm_k(const float* __restrict__ x,
                                                 const float* __restrict__ w,
                                                 bf16_t* __restrict__ ob) {
    const long row = blockIdx.x;
    const float* xr = x + row * DD;
    const int t4 = threadIdx.x * 4;
    float4 v = *(const float4*)(xr + t4);
    float s = v.x*v.x + v.y*v.y + v.z*v.z + v.w*v.w;
    #pragma unroll
    for (int off = 1; off < 64; off <<= 1) s += __shfl_xor(s, off);
    __shared__ float red[4];
    if ((threadIdx.x & 63) == 0) red[threadIdx.x >> 6] = s;
    __syncthreads();
    float tot = red[0] + red[1] + red[2] + red[3];
    float sc = rsqrtf(tot * (1.0f / DD) + 1e-6f);
    float4 wv = *(const float4*)(w + t4);
    bf16x4 o;
    o[0] = (bf16_t)(v.x*sc*wv.x); o[1] = (bf16_t)(v.y*sc*wv.y);
    o[2] = (bf16_t)(v.z*sc*wv.z); o[3] = (bf16_t)(v.w*sc*wv.w);
    *(bf16x4*)(ob + row * DD + t4) = o;
}

// ---------------- causal depthwise conv K=4 (bf16 in, bf16 out) ----------------
__global__ __launch_bounds__(256) void conv_k(const bf16_t* __restrict__ h,
                                              const float* __restrict__ cw,
                                              const float* __restrict__ cb,
                                              bf16_t* __restrict__ hc) {
    const long idx = (long)blockIdx.x * 256 + threadIdx.x;  // over B*T*D
    const int d = (int)(idx & (DD - 1));
    const long bt = idx >> 10;
    const int t = (int)(bt & (TT - 1));
    const float w0 = cw[d*4+0], w1 = cw[d*4+1], w2 = cw[d*4+2], w3 = cw[d*4+3];
    const bf16_t* hp = h + bt * DD + d;
    float acc = cb[d] + (float)hp[0] * w3;
    if (t >= 1) acc += (float)hp[-DD]     * w2;
    if (t >= 2) acc += (float)hp[-2*DD]   * w1;
    if (t >= 3) acc += (float)hp[-3*DD]   * w0;
    hc[idx] = (bf16_t)acc;
}

// ---------------- scan pass1: per-chunk summaries (running-product cd) ----------------
__global__ __launch_bounds__(256) void scan1_k(const bf16_t* __restrict__ ap,
                                               const bf16_t* __restrict__ sp,
                                               float* __restrict__ cd63,
                                               float* __restrict__ i63) {
    const int d = blockIdx.x * 256 + threadIdx.x;  // 0..1023
    const int c = blockIdx.y;                      // chunk 0..63
    const int b = blockIdx.z;                      // batch
    const long rowbase = (long)b * TT + (long)c * 64;
    float cd = 1.0f, rs = 0.0f;
    for (int t = 0; t < 64; t++) {
        const long off = (rowbase + t) * DD + d;
        const float a = (float)ap[off];
        const float s = (float)sp[off];
        const float sig = __builtin_amdgcn_sqrtf(fmaxf(1.0f - a * a, 1e-8f)) * s;
        cd *= fmaxf(a, 1e-10f);
        rs = fmaf(sig, __builtin_amdgcn_rcpf(fmaxf(cd, 1e-10f)), rs);
    }
    const long o = ((long)b * 64 + c) * DD + d;
    cd63[o] = cd;
    i63[o]  = cd * rs;
}

// ---------------- pass2: cross-chunk carry (state ENTERING each chunk) ----------------
__global__ __launch_bounds__(256) void scan2_k(const float* __restrict__ cd63,
                                               const float* __restrict__ i63,
                                               float* __restrict__ carry_in) {
    const int g = blockIdx.x * 256 + threadIdx.x;  // 0..2047
    const int b = g >> 10, d = g & (DD - 1);
    float st = 0.0f;
    for (int c = 0; c < 64; c++) {
        const long o = ((long)b * 64 + c) * DD + d;
        carry_in[o] = st;
        st = i63[o] + cd63[o] * st;
    }
}

// ---------------- pass3: recompute chunk recurrence, fold carry, write bf16 ----------------
__global__ __launch_bounds__(256) void scan3_k(const bf16_t* __restrict__ ap,
                                               const bf16_t* __restrict__ sp,
                                               const float* __restrict__ carry_in,
                                               bf16_t* __restrict__ rec) {
    const int d = blockIdx.x * 256 + threadIdx.x;
    const int c = blockIdx.y;
    const int b = blockIdx.z;
    const long rowbase = (long)b * TT + (long)c * 64;
    const float carry = carry_in[((long)b * 64 + c) * DD + d];
    float cd = 1.0f, rs = 0.0f;
    for (int t = 0; t < 64; t++) {
        const long off = (rowbase + t) * DD + d;
        const float a = (float)ap[off];
        const float s = (float)sp[off];
        const float sig = __builtin_amdgcn_sqrtf(fmaxf(1.0f - a * a, 1e-8f)) * s;
        cd *= fmaxf(a, 1e-10f);
        rs = fmaf(sig, __builtin_amdgcn_rcpf(fmaxf(cd, 1e-10f)), rs);
        rec[off] = (bf16_t)(cd * (rs + carry));
    }
}

// ---------------- bf16 GEMM, C = A(M,K) * B(N,K)^T ----------------
// BM=256, BN=NREP*64, BK=64, 8 waves (2M x 4N), 2-phase K-loop with pre-read
// (R6/R12 structure — best measured; K=1024 regime ceiling ~33% MfmaUtil per
// m248's 848 TF @K=1024 with the full verified technique stack).
// T2 swizzle, T5 setprio, T1 XCD chunk w/ column-major order inside chunk.
enum { EPI_SIGB = 0, EPI_ADDRES = 1, EPI_IV = 2, EPI_GU = 3 };

template<int EPI, int NREP>
__global__ __launch_bounds__(512, 2) void gemm2p_k(const bf16_t* __restrict__ Ag,
                                                   const bf16_t* __restrict__ Bg,
                                                   int M, int N, int K,
                                                   float* outF, bf16_t* outB,
                                                   const float* aux, int ldc) {
    constexpr int BN  = NREP * 64;
    constexpr int ASZ = 16384;        // 256 x 64 bf16
    constexpr int BSZ = BN * 64;
    constexpr int BUF = ASZ + BSZ;
    extern __shared__ bf16_t smem[];  // [2][A | B]
    const int tid = threadIdx.x;
    const int l = tid & 63;
    const int w = tid >> 6;
    const int wm = w >> 2, wn = w & 3;

    const int gx = gridDim.x;
    const int gy = gridDim.y;
    const int lin = blockIdx.y * gx + blockIdx.x;
    long row0, col0;
    if ((gy & 7) == 0) {
        const int rpc = gy >> 3;
        const int q = lin >> 3;
        row0 = (long)((lin & 7) * rpc + q % rpc) * 256;
        col0 = (long)(q / rpc) * (long)BN;
    } else {
        row0 = (long)blockIdx.y * 256;
        col0 = (long)blockIdx.x * BN;
    }

    const int srow = l >> 3;
    const int scol = ((l & 7) ^ srow) * 8;   // pre-swizzled source column
    const long aBase = row0 + srow;
    const long bBase = col0 + srow;
    const int R0a = w * 32;
    const int R0b = w * (BN / 8);

    const int NT = K >> 6;
    f32x4 acc[8][NREP] = {};

    const int lq2 = (l >> 4) * 16;
    const int rA = wm * 128 + (l & 15);
    const int rB = wn * (NREP * 16) + (l & 15);
    const int eA0 = rA * 64 + ((lq2 ^ ((rA & 7) << 4)) >> 1);
    const int eB0 = ASZ + rB * 64 + ((lq2 ^ ((rB & 7) << 4)) >> 1);

    #define STAGE_A(tt, off)                                                          \
        { const long kgk = (long)(tt) * 64 + scol;                                    \
          _Pragma("unroll")                                                           \
          for (int i = 0; i < 4; i++)                                                 \
              gload16(Ag + (aBase + R0a + i * 8) * (long)K + kgk,                     \
                      &smem[(off) + (R0a + i * 8) * 64]); }
    #define STAGE_B(tt, off)                                                          \
        { const long kgk = (long)(tt) * 64 + scol;                                    \
          _Pragma("unroll")                                                           \
          for (int i = 0; i < NREP; i++)                                              \
              gload16(Bg + (bBase + R0b + i * 8) * (long)K + kgk,                     \
                      &smem[(off) + ASZ + (R0b + i * 8) * 64]); }

    STAGE_A(0, 0); STAGE_B(0, 0);
    STAGE_A(1, BUF); STAGE_B(1, BUF);
    if constexpr (NREP == 4) { asm volatile("s_waitcnt vmcnt(8)" ::: "memory"); }
    else                     { asm volatile("s_waitcnt vmcnt(6)" ::: "memory"); }
    asm volatile("s_barrier" ::: "memory");

    bf16x8 pA[2][4], pB[2][NREP];
    #pragma unroll
    for (int kk = 0; kk < 2; kk++) {
        const int xo = kk * 32;
        #pragma unroll
        for (int n = 0; n < NREP; n++)
            pB[kk][n] = *(const bf16x8*)&smem[(eB0 ^ xo) + n * 1024];
        #pragma unroll
        for (int m = 0; m < 4; m++)
            pA[kk][m] = *(const bf16x8*)&smem[(eA0 ^ xo) + m * 1024];
    }

    for (int t = 0; t < NT; t++) {
        const int co = (t & 1) ? BUF : 0;
        const int oo = BUF - co;
        bf16x8 a1[2][4];

        __builtin_amdgcn_s_setprio(1);
        #pragma unroll
        for (int kk = 0; kk < 2; kk++)
            #pragma unroll
            for (int m = 0; m < 4; m++)
                #pragma unroll
                for (int n = 0; n < NREP; n++)
                    acc[m][n] = __builtin_amdgcn_mfma_f32_16x16x32_bf16(pA[kk][m], pB[kk][n], acc[m][n], 0, 0, 0);
        __builtin_amdgcn_s_setprio(0);
        #pragma unroll
        for (int kk = 0; kk < 2; kk++) {
            const int xo = kk * 32;
            #pragma unroll
            for (int m = 0; m < 4; m++)
                a1[kk][m] = *(const bf16x8*)&smem[co + (eA0 ^ xo) + 4096 + m * 1024];
        }
        asm volatile("s_barrier" ::: "memory");

        if (t + 2 < NT) { STAGE_A(t + 2, co); STAGE_B(t + 2, co); }
        __builtin_amdgcn_s_setprio(1);
        #pragma unroll
        for (int kk = 0; kk < 2; kk++)
            #pragma unroll
            for (int m = 0; m < 4; m++)
                #pragma unroll
                for (int n = 0; n < NREP; n++)
                    acc[m + 4][n] = __builtin_amdgcn_mfma_f32_16x16x32_bf16(a1[kk][m], pB[kk][n], acc[m + 4][n], 0, 0, 0);
        __builtin_amdgcn_s_setprio(0);
        if (t + 2 < NT) {
            if constexpr (NREP == 4) { asm volatile("s_waitcnt vmcnt(8)" ::: "memory"); }
            else                     { asm volatile("s_waitcnt vmcnt(6)" ::: "memory"); }
        } else if (t + 1 < NT) {
            asm volatile("s_waitcnt vmcnt(0)" ::: "memory");
        }
        asm volatile("s_barrier" ::: "memory");
        if (t + 1 < NT) {
            #pragma unroll
            for (int kk = 0; kk < 2; kk++) {
                const int xo = kk * 32;
                #pragma unroll
                for (int n = 0; n < NREP; n++)
                    pB[kk][n] = *(const bf16x8*)&smem[oo + (eB0 ^ xo) + n * 1024];
                #pragma unroll
                for (int m = 0; m < 4; m++)
                    pA[kk][m] = *(const bf16x8*)&smem[oo + (eA0 ^ xo) + m * 1024];
            }
        }
    }
    #undef STAGE_A
    #undef STAGE_B

    #pragma unroll
    for (int m = 0; m < 8; m++) {
        const long r0 = row0 + wm * 128 + m * 16 + (l >> 4) * 4;
        #pragma unroll
        for (int n = 0; n < NREP; n++) {
            const long cc = col0 + wn * (NREP * 16) + n * 16 + (l & 15);
            f32x4 v = acc[m][n];
            #pragma unroll
            for (int j = 0; j < 4; j++) {
                const long r = r0 + j;
                const float xv = v[j];
                if (EPI == EPI_SIGB) {
                    outB[r * ldc + cc] = (bf16_t)(1.0f / (1.0f + __expf(-(xv + aux[cc]))));
                } else if (EPI == EPI_ADDRES) {
                    outF[r * ldc + cc] = xv + aux[r * ldc + cc];
                } else if (EPI == EPI_IV) {
                    const float px = __shfl_xor(xv, 1);
                    if ((l & 1) == 0)
                        outB[r * ldc + (cc >> 1)] = (bf16_t)(px / (1.0f + __expf(-xv)));
                } else {  // EPI_GU
                    const float px = __shfl_xor(xv, 1);
                    if ((l & 1) == 0)
                        outB[r * ldc + (cc >> 1)] = (bf16_t)(xv / (1.0f + __expf(-xv)) * px);
                }
            }
        }
    }
}

extern "C" void kernel_launch(void* const* d_in, const int* in_sizes, int n_in,
                              void* d_out, int out_size, void* d_ws, size_t ws_size,
                              hipStream_t stream) {
    const float* x   = (const float*)d_in[0];
    const float* pnw = (const float*)d_in[1];
    const float* cw  = (const float*)d_in[2];
    const float* cb  = (const float*)d_in[3];
    const float* wa  = (const float*)d_in[4];
    const float* wi  = (const float*)d_in[5];
    const float* wv  = (const float*)d_in[6];
    const float* wop = (const float*)d_in[7];
    const float* db  = (const float*)d_in[8];
    const float* fnw = (const float*)d_in[9];
    const float* wgu = (const float*)d_in[10];
    const float* wdn = (const float*)d_in[11];
    float* out = (float*)d_out;

    // ---- workspace layout (total ~129.5 MiB) ----
    char* ws = (char*)d_ws;
    bf16_t* wab   = (bf16_t*)(ws + 0);            // 1024x1024 bf16
    bf16_t* wivb  = (bf16_t*)(ws + 2097152);      // 2048x1024 bf16 (i|v interleaved)
    bf16_t* wopb  = (bf16_t*)(ws + 6291456);      // 1024x1024 bf16
    bf16_t* wgub  = (bf16_t*)(ws + 8388608);      // 8192x1024 bf16 (gate|up interleaved)
    bf16_t* wdnb  = (bf16_t*)(ws + 25165824);     // 4096x1024 bf16
    bf16_t* hb    = (bf16_t*)(ws + 33554432);     // 8192x1024 bf16 (reused: hn)
    bf16_t* hn    = hb;
    bf16_t* hc    = (bf16_t*)(ws + 50331648);     // 8192x1024 bf16 (reused: rec)
    bf16_t* rec   = hc;
    bf16_t* a_b   = (bf16_t*)(ws + 67108864);     // 8192x1024 bf16 (a-plane)
    bf16_t* s_b   = (bf16_t*)(ws + 100663296);    // 8192x1024 bf16 (s-plane)
    bf16_t* act   = (bf16_t*)(ws + 67108864);     // 8192x4096 bf16 (overlays after scan)
    float*  cd63  = (float*)(ws + 134217728);
    float*  i63   = (float*)(ws + 134742016);
    float*  carry = (float*)(ws + 135266304);

    const int LDS4 = 131072;   // NREP=4
    const int LDS2 = 98304;    // NREP=2
    hipFuncSetAttribute((const void*)gemm2p_k<EPI_SIGB, 2>,   hipFuncAttributeMaxDynamicSharedMemorySize, LDS2);
    hipFuncSetAttribute((const void*)gemm2p_k<EPI_IV, 4>,     hipFuncAttributeMaxDynamicSharedMemorySize, LDS4);
    hipFuncSetAttribute((const void*)gemm2p_k<EPI_ADDRES, 2>, hipFuncAttributeMaxDynamicSharedMemorySize, LDS2);
    hipFuncSetAttribute((const void*)gemm2p_k<EPI_GU, 4>,     hipFuncAttributeMaxDynamicSharedMemorySize, LDS4);

    // merged weight convert (1 kernel, 16M elements)
    cvt_all_k<<<16384, 256, 0, stream>>>(wa, wop, wdn, wi, wv, wgu,
                                         wab, wopb, wdnb, wivb, wgub);

    // pre-norm + conv
    rmsnorm_k<<<8192, 256, 0, stream>>>(x, pnw, hb);
    conv_k<<<32768, 256, 0, stream>>>(hb, cw, cb, hc);

    // a-plane (bf16): sigmoid(h*w_a^T + db);  s-plane (bf16): sigmoid(h*w_i^T) * (h*w_v^T)
    gemm2p_k<EPI_SIGB, 2><<<dim3(8, 32), 512, LDS2, stream>>>(hc, wab,  8192, 1024, 1024,
                                                              nullptr, a_b, db, 1024);
    gemm2p_k<EPI_IV, 4>  <<<dim3(8, 32), 512, LDS4, stream>>>(hc, wivb, 8192, 2048, 1024,
                                                              nullptr, s_b, nullptr, 1024);
    // chunked scan (reference's clipped formula; running-product cd)
    scan1_k<<<dim3(4, 64, 2), 256, 0, stream>>>(a_b, s_b, cd63, i63);
    scan2_k<<<8, 256, 0, stream>>>(cd63, i63, carry);
    scan3_k<<<dim3(4, 64, 2), 256, 0, stream>>>(a_b, s_b, carry, rec);

    // out_proj + residual -> d_out holds x2
    gemm2p_k<EPI_ADDRES, 2><<<dim3(8, 32), 512, LDS2, stream>>>(rec, wopb, 8192, 1024, 1024,
                                                                out, nullptr, x, 1024);
    // ffn
    rmsnorm_k<<<8192, 256, 0, stream>>>(out, fnw, hn);
    gemm2p_k<EPI_GU, 4><<<dim3(32, 32), 512, LDS4, stream>>>(hn, wgub, 8192, 8192, 1024,
                                                             nullptr, act, nullptr, 4096);
    // down-proj + residual, in place on d_out
    gemm2p_k<EPI_ADDRES, 2><<<dim3(8, 32), 512, LDS2, stream>>>(act, wdnb, 8192, 1024, 4096,
                                                                out, nullptr, out, 1024);
}